// Round 1
// 19001.472 us; speedup vs baseline: 1.1710x; 1.1710x over previous
//
#include <hip/hip_runtime.h>
#include <math.h>

// ---------------- ws layout (float offsets), total ~119.4 MiB ----------------
#define WS_C3   0u
#define WS_C2CH 22413312u
#define WS_AC   28104192u
#define WS_A1   0u
#define WS_ST   31249920u

__device__ __forceinline__ float sigm(float x){ return 1.0f / (1.0f + expf(-x)); }

// Fine-grained coherent access (sc0 sc1): bypasses L1/L2, served at the
// coherence point — cross-XCD visible without cache flushes.
__device__ __forceinline__ void cstore(float* p, float v){
  union { float f; unsigned u; } c; c.f = v;
  __hip_atomic_store((unsigned*)p, c.u, __ATOMIC_RELAXED,
                     __HIP_MEMORY_SCOPE_SYSTEM);
}
__device__ __forceinline__ void cload64(const float* p, float& a, float& b){
  unsigned long long u = __hip_atomic_load((const unsigned long long*)p,
                          __ATOMIC_RELAXED, __HIP_MEMORY_SCOPE_SYSTEM);
  union { unsigned long long u; float f[2]; } c; c.u = u;
  a = c.f[0]; b = c.f[1];
}
__device__ __forceinline__ unsigned cloadu(const unsigned* p){
  return __hip_atomic_load(p, __ATOMIC_RELAXED, __HIP_MEMORY_SCOPE_SYSTEM);
}
__device__ __forceinline__ unsigned long long cloadu64(const void* p){
  return __hip_atomic_load((const unsigned long long*)p, __ATOMIC_RELAXED,
                           __HIP_MEMORY_SCOPE_SYSTEM);
}
__device__ __forceinline__ void cstoreu64(void* p, unsigned long long v){
  __hip_atomic_store((unsigned long long*)p, v, __ATOMIC_RELAXED,
                     __HIP_MEMORY_SCOPE_SYSTEM);
}

// Fully distributed grid barrier — no address has more than ONE reader or
// concurrent-writer set that serializes:
//   arrival slots sy[16 + wg*16]   (256 lines, writer=wg, reader=wg255)
//   flag copies   sy[4112 + wg*16] (256 lines, writer=wg255, reader=wg)
// wg255 wave0 polls all 256 slots (4/lane), then ALL 256 threads of wg255
// store bar into the 256 flag lines; each other WG polls its own flag line.
#define SLOT 16
#define FLG  4112
// argmax/emb producer slots: 88 lines, one u64 per line:
//   hi32 = step tag (t+1 after stage C' of step t), lo32 = 8 x 4-bit states.
// Tag+data in ONE atomic u64 => consumers need no fence, just the load.
#define SLOTX 8208
__device__ __forceinline__ void gbar(unsigned* sy, unsigned bar, int wg){
  __syncthreads();   // drains vmcnt(0): all coherent data stores visible
  const int tid = threadIdx.x;
  if (tid == 0)
    __hip_atomic_store(&sy[SLOT + wg*16], bar, __ATOMIC_RELAXED,
                       __HIP_MEMORY_SCOPE_SYSTEM);
  if (wg == 255){
    if (tid < 64){
      for (;;){
        unsigned m0 = cloadu(&sy[SLOT + (4*tid + 0)*16]);
        unsigned m1 = cloadu(&sy[SLOT + (4*tid + 1)*16]);
        unsigned m2 = cloadu(&sy[SLOT + (4*tid + 2)*16]);
        unsigned m3 = cloadu(&sy[SLOT + (4*tid + 3)*16]);
        unsigned a = m0 < m1 ? m0 : m1;
        unsigned b = m2 < m3 ? m2 : m3;
        unsigned mn = a < b ? a : b;
        if (__all(mn >= bar)) break;
        __builtin_amdgcn_s_sleep(1);
      }
    }
    __syncthreads();   // orders poll completion before flag release
    __hip_atomic_store(&sy[FLG + tid*16], bar, __ATOMIC_RELAXED,
                       __HIP_MEMORY_SCOPE_SYSTEM);
  } else {
    if (tid == 0){
      while (cloadu(&sy[FLG + wg*16]) < bar)
        __builtin_amdgcn_s_sleep(1);
    }
  }
  __syncthreads();
}

// ------- conv2f: fused conv1+bn1+relu -> conv2+bn2+relu+pool(1,2) -------
__global__ __launch_bounds__(256) void conv2f_k(
    const float* __restrict__ mel, const float* __restrict__ w1,
    const float* __restrict__ b1, const float* __restrict__ g1,
    const float* __restrict__ be1, const float* __restrict__ m1,
    const float* __restrict__ v1,
    const float* __restrict__ w2, const float* __restrict__ b2,
    const float* __restrict__ g2, const float* __restrict__ be2,
    const float* __restrict__ m2, const float* __restrict__ v2,
    float* __restrict__ c2ch, int t0)
{
  __shared__ float act[3*8*240];
  __shared__ float w2s[48*8*12];
  __shared__ float mel5[5*240];
  __shared__ float w1s[48*12];
  __shared__ float sc1[48], sh1[48], sc2[48], sh2[48];
  int tid = threadIdx.x;
  int b = blockIdx.x / 130, lt = blockIdx.x - b*130;
  int t = t0 - 1 + lt;

  int fg = tid % 29, ocg = tid / 29;
  int f0 = fg * 8, oc0 = ocg * 6;

  if (t < 0 || t > 511){
    if (tid < 232){
      for (int o = 0; o < 6; ++o)
        for (int jj = 0; jj < 4; ++jj){
          int fp = fg*4 + jj;
          if (fp < 114)
            c2ch[((b*48 + oc0 + o)*130 + lt)*114 + fp] = 0.f;
        }
    }
    return;
  }

  for (int idx = tid; idx < 5*240; idx += 256){
    int rr = idx / 240, w = idx - rr*240;
    int tt = t + rr - 2, f = w - 2;
    mel5[idx] = (tt >= 0 && tt < 512 && f >= 0 && f < 229)
                ? mel[(b*512 + tt)*229 + f] : 0.f;
  }
  for (int idx = tid; idx < 48*12; idx += 256){
    int c = idx / 12, q = idx - c*12;
    int kh = q >> 2, kw = q & 3;
    w1s[idx] = (kw < 3) ? w1[c*9 + kh*3 + kw] : 0.f;
  }
  if (tid < 48){
    float s1 = g1[tid] / sqrtf(v1[tid] + 1e-5f);
    sc1[tid] = s1; sh1[tid] = be1[tid] + (b1[tid] - m1[tid]) * s1;
    float s2 = g2[tid] / sqrtf(v2[tid] + 1e-5f);
    sc2[tid] = s2; sh2[tid] = be2[tid] + (b2[tid] - m2[tid]) * s2;
  }

  float acc[6][8];
  #pragma unroll
  for (int o = 0; o < 6; ++o)
    #pragma unroll
    for (int j = 0; j < 8; ++j) acc[o][j] = 0.f;

  for (int ch = 0; ch < 6; ++ch){
    int ci0 = ch * 8;
    __syncthreads();
    for (int idx = tid; idx < 3*8*240; idx += 256){
      int rr = idx / 1920;
      int rem = idx - rr*1920;
      int ci = rem / 240, w = rem - ci*240;
      int tt = t + rr - 1, f = w - 1;
      float val = 0.f;
      if (tt >= 0 && tt < 512 && f >= 0 && f < 229){
        int cg = ci0 + ci;
        float a = 0.f;
        #pragma unroll
        for (int dh = 0; dh < 3; ++dh){
          const float* mr = &mel5[(rr + dh)*240 + w];
          a = fmaf(mr[0], w1s[cg*12 + dh*4 + 0], a);
          a = fmaf(mr[1], w1s[cg*12 + dh*4 + 1], a);
          a = fmaf(mr[2], w1s[cg*12 + dh*4 + 2], a);
        }
        a = a * sc1[cg] + sh1[cg];
        val = a > 0.f ? a : 0.f;
      }
      act[idx] = val;
    }
    for (int idx = tid; idx < 48*8*12; idx += 256){
      int oc = idx / 96;
      int rem = idx - oc*96;
      int ci = rem / 12, q = rem - ci*12;
      int kh = q >> 2, kw = q & 3;
      w2s[idx] = (kw < 3) ? w2[(oc*48 + ci0 + ci)*9 + kh*3 + kw] : 0.f;
    }
    __syncthreads();
    if (tid < 232){
      for (int ci = 0; ci < 8; ++ci){
        #pragma unroll
        for (int kh = 0; kh < 3; ++kh){
          const float* ap = &act[(kh*8 + ci)*240 + f0];
          float4 A0 = *(const float4*)(ap);
          float4 A1v = *(const float4*)(ap + 4);
          float4 A2 = *(const float4*)(ap + 8);
          float L[12] = {A0.x,A0.y,A0.z,A0.w,A1v.x,A1v.y,A1v.z,A1v.w,A2.x,A2.y,A2.z,A2.w};
          #pragma unroll
          for (int o = 0; o < 6; ++o){
            float4 wv = *(const float4*)&w2s[((oc0 + o)*8 + ci)*12 + kh*4];
            #pragma unroll
            for (int j = 0; j < 8; ++j)
              acc[o][j] = fmaf(L[j+2], wv.z, fmaf(L[j+1], wv.y, fmaf(L[j], wv.x, acc[o][j])));
          }
        }
      }
    }
  }
  __syncthreads();
  if (tid < 232){
    #pragma unroll
    for (int o = 0; o < 6; ++o){
      int oc = oc0 + o;
      float s = sc2[oc], hs = sh2[oc];
      #pragma unroll
      for (int jj = 0; jj < 4; ++jj){
        int fp = fg*4 + jj;
        if (fp < 114){
          float v0 = acc[o][2*jj] * s + hs;   v0 = v0 > 0.f ? v0 : 0.f;
          float v1 = acc[o][2*jj+1] * s + hs; v1 = v1 > 0.f ? v1 : 0.f;
          c2ch[((b*48 + oc)*130 + lt)*114 + fp] = v0 > v1 ? v0 : v1;
        }
      }
    }
  }
}

// ------- conv3 (48->96) + bn + relu + pool(1,2) -------
__global__ __launch_bounds__(256) void conv3_k(
    const float* __restrict__ c2ch, const float* __restrict__ w3,
    const float* __restrict__ b3, const float* __restrict__ g3,
    const float* __restrict__ be3, const float* __restrict__ m3,
    const float* __restrict__ v3, float* __restrict__ c3p, int t0)
{
  __shared__ float act[3*8*128];
  __shared__ float w3s[96*8*12];
  __shared__ float sc[96], sh[96];
  int tid = threadIdx.x;
  int b = blockIdx.x >> 7, tl = blockIdx.x & 127;
  int t = t0 + tl;
  if (tid < 96){
    float s = g3[tid] / sqrtf(v3[tid] + 1e-5f);
    sc[tid] = s; sh[tid] = be3[tid] + (b3[tid] - m3[tid]) * s;
  }
  int fg = tid % 15, ocg = tid / 15;
  int f0 = fg * 8, oc0 = ocg * 6;
  float acc[6][8];
  #pragma unroll
  for (int o = 0; o < 6; ++o)
    #pragma unroll
    for (int j = 0; j < 8; ++j) acc[o][j] = 0.f;

  for (int ch = 0; ch < 6; ++ch){
    int ci0 = ch * 8;
    __syncthreads();
    for (int idx = tid; idx < 3*8*128; idx += 256){
      int rr = idx >> 10;
      int rem = idx & 1023;
      int ci = rem >> 7, w = rem & 127;
      int lt = tl + rr;
      int f = w - 1;
      float val = 0.f;
      if (f >= 0 && f < 114)
        val = c2ch[((b*48 + ci0 + ci)*130 + lt)*114 + f];
      act[idx] = val;
    }
    for (int idx = tid; idx < 96*8*12; idx += 256){
      int oc = idx / 96;
      int rem = idx - oc*96;
      int ci = rem / 12, q = rem - ci*12;
      int kh = q >> 2, kw = q & 3;
      w3s[idx] = (kw < 3) ? w3[(oc*48 + ci0 + ci)*9 + kh*3 + kw] : 0.f;
    }
    __syncthreads();
    if (tid < 240){
      for (int ci = 0; ci < 8; ++ci){
        #pragma unroll
        for (int kh = 0; kh < 3; ++kh){
          const float* ap = &act[(kh*8 + ci)*128 + f0];
          float4 A0 = *(const float4*)(ap);
          float4 A1v = *(const float4*)(ap + 4);
          float4 A2 = *(const float4*)(ap + 8);
          float L[12] = {A0.x,A0.y,A0.z,A0.w,A1v.x,A1v.y,A1v.z,A1v.w,A2.x,A2.y,A2.z,A2.w};
          #pragma unroll
          for (int o = 0; o < 6; ++o){
            float4 wv = *(const float4*)&w3s[((oc0 + o)*8 + ci)*12 + kh*4];
            #pragma unroll
            for (int j = 0; j < 8; ++j)
              acc[o][j] = fmaf(L[j+2], wv.z, fmaf(L[j+1], wv.y, fmaf(L[j], wv.x, acc[o][j])));
          }
        }
      }
    }
  }
  __syncthreads();
  if (tid < 240){
    #pragma unroll
    for (int o = 0; o < 6; ++o){
      int oc = oc0 + o;
      float s = sc[oc], hs = sh[oc];
      #pragma unroll
      for (int jj = 0; jj < 4; ++jj){
        int fp = fg*4 + jj;
        if (fp < 57){
          float v0 = acc[o][2*jj] * s + hs;   v0 = v0 > 0.f ? v0 : 0.f;
          float v1 = acc[o][2*jj+1] * s + hs; v1 = v1 > 0.f ? v1 : 0.f;
          c3p[((b*96 + oc)*512 + t)*57 + fp] = v0 > v1 ? v0 : v1;
        }
      }
    }
  }
}

// ------- GEMM: acoustic = conv_feat @ fc_w.T + fc_b -------
__global__ __launch_bounds__(256) void gemm_fc_k(
    const float* __restrict__ c3p, const float* __restrict__ fcw,
    const float* __restrict__ fcb, float* __restrict__ ac)
{
  __shared__ float As[16*132];
  __shared__ float Bs[16*132];
  int tid = threadIdx.x;
  int m0 = blockIdx.x * 128, n0 = blockIdx.y * 128;
  int tm = (tid & 15) * 8, tn = (tid >> 4) * 8;
  float acc[8][8];
  #pragma unroll
  for (int i = 0; i < 8; ++i)
    #pragma unroll
    for (int j = 0; j < 8; ++j) acc[i][j] = 0.f;

  for (int k0 = 0; k0 < 5472; k0 += 16){
    __syncthreads();
    #pragma unroll
    for (int i = 0; i < 8; ++i){
      int idx = i*256 + tid;
      int k = idx & 15, mm = idx >> 4;
      int gk = k0 + k;
      int ci = (gk * 36793) >> 21;
      int f  = gk - ci*57;
      int gm = m0 + mm;
      int bb = gm >> 9, tt = gm & 511;
      As[k*132 + mm] = c3p[((bb*96 + ci)*512 + tt)*57 + f];
      Bs[k*132 + mm] = fcw[(n0 + mm)*5472 + gk];
    }
    __syncthreads();
    #pragma unroll
    for (int k = 0; k < 16; ++k){
      const float* arow = &As[k*132 + tm];
      const float* brow = &Bs[k*132 + tn];
      float4 a0 = *(const float4*)arow, a1 = *(const float4*)(arow + 4);
      float4 b0 = *(const float4*)brow, b1 = *(const float4*)(brow + 4);
      float av[8] = {a0.x,a0.y,a0.z,a0.w,a1.x,a1.y,a1.z,a1.w};
      float bv[8] = {b0.x,b0.y,b0.z,b0.w,b1.x,b1.y,b1.z,b1.w};
      #pragma unroll
      for (int i = 0; i < 8; ++i)
        #pragma unroll
        for (int j = 0; j < 8; ++j)
          acc[i][j] = fmaf(av[i], bv[j], acc[i][j]);
    }
  }
  #pragma unroll
  for (int i = 0; i < 8; ++i){
    int gm = m0 + tm + i;
    #pragma unroll
    for (int j = 0; j < 8; ++j){
      int gn = n0 + tn + j;
      ac[gm*768 + gn] = acc[i][j] + fcb[gn];
    }
  }
}

// ------- GEMM: A1[t][row][b] = acoustic @ wih1[:, :768].T + bih1+bhh1 -------
__global__ __launch_bounds__(256) void gemm_a1_k(
    const float* __restrict__ ac, const float* __restrict__ wih1,
    const float* __restrict__ bih1, const float* __restrict__ bhh1,
    float* __restrict__ A1)
{
  __shared__ float As[16*132];
  __shared__ float Bs[16*132];
  int tid = threadIdx.x;
  int m0 = blockIdx.x * 128, n0 = blockIdx.y * 128;
  int tm = (tid & 15) * 8, tn = (tid >> 4) * 8;
  float acc[8][8];
  #pragma unroll
  for (int i = 0; i < 8; ++i)
    #pragma unroll
    for (int j = 0; j < 8; ++j) acc[i][j] = 0.f;

  for (int k0 = 0; k0 < 768; k0 += 16){
    __syncthreads();
    #pragma unroll
    for (int i = 0; i < 8; ++i){
      int idx = i*256 + tid;
      int k = idx & 15, mm = idx >> 4;
      int gk = k0 + k;
      As[k*132 + mm] = ac[(m0 + mm)*768 + gk];
      Bs[k*132 + mm] = wih1[(n0 + mm)*944 + gk];
    }
    __syncthreads();
    #pragma unroll
    for (int k = 0; k < 16; ++k){
      const float* arow = &As[k*132 + tm];
      const float* brow = &Bs[k*132 + tn];
      float4 a0 = *(const float4*)arow, a1 = *(const float4*)(arow + 4);
      float4 b0 = *(const float4*)brow, b1 = *(const float4*)(brow + 4);
      float av[8] = {a0.x,a0.y,a0.z,a0.w,a1.x,a1.y,a1.z,a1.w};
      float bv[8] = {b0.x,b0.y,b0.z,b0.w,b1.x,b1.y,b1.z,b1.w};
      #pragma unroll
      for (int i = 0; i < 8; ++i)
        #pragma unroll
        for (int j = 0; j < 8; ++j)
          acc[i][j] = fmaf(av[i], bv[j], acc[i][j]);
    }
  }
  #pragma unroll
  for (int i = 0; i < 8; ++i){
    int gm = m0 + tm + i;
    int tt = gm & 511, bb = gm >> 9;
    #pragma unroll
    for (int j = 0; j < 8; ++j){
      int gn = n0 + tn + j;
      A1[tt*24576 + gn*8 + bb] = acc[i][j] + bih1[gn] + bhh1[gn];
    }
  }
}

// ---------------- persistent recurrent kernel ----------------
// Restructure vs previous version:
//  * stage A no longer stages from global: xs (LDS) persists h1n(t-1) staged
//    by stage B(t-1) — the two stagings were byte-identical.
//  * emb feedback is slot-based: stage C' packs 8 batches' argmax states +
//    step tag into ONE u64 system store per pitch; stage A(t+1) polls the 88
//    slots (overlapped behind its dot products) and applies the emb term via
//    a precomputed per-WG LDS table cvec[p][s][row]. This removes the third
//    grid barrier per step entirely (2 gbars/step instead of 3).
//  * stage C' logits read h2n straight into registers (no LDS round trip);
//    the same registers feed the h2s ds_writes for stage B(t+1).
//  * stage B computes the h2 half of the gates (operands already in h2s)
//    while its 12 h1 staging loads are in flight.
#define S2 772
__global__ __launch_bounds__(256, 1) void rec_k(
    const float* __restrict__ A1,
    const float* __restrict__ whh1, const float* __restrict__ wih1,
    const float* __restrict__ wih2, const float* __restrict__ whh2,
    const float* __restrict__ bih2, const float* __restrict__ bhh2,
    const float* __restrict__ postw, const float* __restrict__ postb,
    const float* __restrict__ embw,
    float* __restrict__ xbuf, float* __restrict__ h2b,
    unsigned* __restrict__ sy, float* __restrict__ out)
{
  const int wg = blockIdx.x, tid = threadIdx.x;
  const int wv = tid >> 6, l = tid & 63;
  __shared__ float xs[8*S2];      // h1 carrier: staged by stage B, reused by A
  __shared__ float h2s[8*S2];     // h2(t-1) planes, staged by stage C'
  __shared__ float cvec[88*5*12]; // emb contribution per (pitch,state,row)
  __shared__ float zbuf[96];
  __shared__ float red2[160];
  __shared__ unsigned smax[88];

  float wA[12][3];
  float wB[24][3];
  float wC[3][5];
  {
    int Rb = wv*768 + wg*3;
    #pragma unroll
    for (int ki = 0; ki < 12; ++ki){
      int k = l + (ki << 6);
      #pragma unroll
      for (int u = 0; u < 3; ++u)
        wA[ki][u] = whh1[(Rb + u)*768 + k];
    }
    #pragma unroll
    for (int ki = 0; ki < 24; ++ki){
      int k = l + (ki << 6);
      #pragma unroll
      for (int u = 0; u < 3; ++u)
        wB[ki][u] = (k < 768) ? wih2[(Rb + u)*768 + k] : whh2[(Rb + u)*768 + k - 768];
    }
  }
  if (wg < 88){
    #pragma unroll
    for (int kc = 0; kc < 3; ++kc)
      #pragma unroll
      for (int s = 0; s < 5; ++s)
        wC[kc][s] = postw[(wg*5 + s)*768 + tid + (kc << 8)];
  }
  float b2r = 0.f; int fR = 0, fb = 0;
  if (tid < 96){
    int g = tid / 24, rem = tid - g*24;
    int u = rem >> 3; fb = rem & 7;
    fR = g*768 + wg*3 + u;
    b2r = bih2[fR] + bhh2[fR];
  }
  float pbr = (wg < 88 && tid < 40) ? postb[wg*5 + (tid >> 3)] : 0.f;
  float c1r = 0.f, c2r = 0.f;

  // cvec[(p*5+s)*12 + (g*3+u)] = emb contribution of pitch p in state s to
  // this WG's gate row (g*768 + wg*3 + u). Computed once.
  for (int idx = tid; idx < 88*5*12; idx += 256){
    int p = idx / 60, rem = idx - p*60;
    int s = rem / 12, r = rem - s*12;
    int g = r / 3, u = r - g*3;
    int row = g*768 + wg*3 + u;
    cvec[idx] = wih1[row*944 + 768 + 2*p]     * embw[s*2]
              + wih1[row*944 + 768 + 2*p + 1] * embw[s*2 + 1];
  }
  for (int idx = tid; idx < 8*S2; idx += 256){ h2s[idx] = 0.f; xs[idx] = 0.f; }
  __syncthreads();   // global state already zeroed by stream-ordered memset

  unsigned bar = 0;

  for (int t = 0; t < 512; ++t){
    const int nxt = (t & 1) ^ 1;
    float* xn  = xbuf + nxt * 7552;
    float* h2n = h2b + nxt * 6144;

    float a1v = 0.f;
    if (tid < 96) a1v = A1[t*24576 + fR*8 + fb];

    // ---- stage A: gates1 = A1[t] + whh1@h1 (from xs) + emb (from slots) ----
    {
      float acc[3][8];
      #pragma unroll
      for (int u = 0; u < 3; ++u)
        #pragma unroll
        for (int j = 0; j < 8; ++j) acc[u][j] = 0.f;
      #pragma unroll
      for (int ki = 0; ki < 12; ++ki){
        int k = l + (ki << 6);
        float x0 = xs[k],        x1 = xs[S2 + k],   x2 = xs[2*S2 + k], x3 = xs[3*S2 + k];
        float x4 = xs[4*S2 + k], x5 = xs[5*S2 + k], x6 = xs[6*S2 + k], x7 = xs[7*S2 + k];
        #pragma unroll
        for (int u = 0; u < 3; ++u){
          float w = wA[ki][u];
          acc[u][0] = fmaf(w, x0, acc[u][0]);
          acc[u][1] = fmaf(w, x1, acc[u][1]);
          acc[u][2] = fmaf(w, x2, acc[u][2]);
          acc[u][3] = fmaf(w, x3, acc[u][3]);
          acc[u][4] = fmaf(w, x4, acc[u][4]);
          acc[u][5] = fmaf(w, x5, acc[u][5]);
          acc[u][6] = fmaf(w, x6, acc[u][6]);
          acc[u][7] = fmaf(w, x7, acc[u][7]);
        }
      }
      __syncthreads();   // S1: prior-step zbuf/red2 readers done
      #pragma unroll
      for (int u = 0; u < 3; ++u)
        #pragma unroll
        for (int j = 0; j < 8; ++j){
          float s = acc[u][j];
          s += __shfl_xor(s, 1);  s += __shfl_xor(s, 2);  s += __shfl_xor(s, 4);
          s += __shfl_xor(s, 8);  s += __shfl_xor(s, 16); s += __shfl_xor(s, 32);
          if (l == 0) zbuf[wv*24 + u*8 + j] = s;
        }
      // wave0 polls the 88 argmax slots (tag >= t; t=0 passes on memset zeros).
      // Producers wrote them right after B-bar(t-1), so this normally hits
      // immediately — the wait is hidden behind the dot products above.
      if (wv == 0){
        unsigned long long* sl = (unsigned long long*)&sy[SLOTX];
        unsigned lo0 = 0, lo1 = 0;
        for (;;){
          unsigned long long v0 = cloadu64(&sl[l*8]);
          unsigned long long v1 = 0xffffffffffffffffull;
          if (l < 24) v1 = cloadu64(&sl[(64 + l)*8]);
          unsigned t0v = (unsigned)(v0 >> 32);
          unsigned t1v = (unsigned)(v1 >> 32);
          unsigned mn = t0v < t1v ? t0v : t1v;
          if (__all(mn >= (unsigned)t)){ lo0 = (unsigned)v0; lo1 = (unsigned)v1; break; }
          __builtin_amdgcn_s_sleep(1);
        }
        smax[l] = lo0;
        if (l < 24) smax[64 + l] = lo1;
      }
      __syncthreads();   // S2
      if (tid < 96){
        int g = tid / 24;
        int rowidx = g*3 + ((tid - g*24) >> 3);
        int b = tid & 7;
        float z = zbuf[tid] + a1v;
        for (int p = 0; p < 88; ++p){
          int s = (smax[p] >> (b*4)) & 7;
          z += cvec[(p*5 + s)*12 + rowidx];
        }
        zbuf[tid] = z;
      }
      __syncthreads();   // S3
      if (tid < 24){
        float zi = zbuf[tid], zf = zbuf[24 + tid], zg = zbuf[48 + tid], zo = zbuf[72 + tid];
        c1r = sigm(zf)*c1r + sigm(zi)*tanhf(zg);
        float hh = sigm(zo)*tanhf(c1r);
        cstore(&xn[(wg*3 + (tid >> 3))*8 + (tid & 7)], hh);
      }
      ++bar; gbar(sy, bar, wg);
    }

    // ---- stage B: gates2 = h1n @ wih2.T + h2(t-1)[h2s] @ whh2.T + b ----
    {
      float sa[12], sb[12];
      #pragma unroll
      for (int i = 0; i < 12; ++i){
        int idx = tid + (i << 8);
        cload64(xn + 2*idx, sa[i], sb[i]);
      }
      float acc[3][8];
      #pragma unroll
      for (int u = 0; u < 3; ++u)
        #pragma unroll
        for (int j = 0; j < 8; ++j) acc[u][j] = 0.f;
      // h2 half first: operands already in LDS, hides the loads above
      #pragma unroll
      for (int ki = 12; ki < 24; ++ki){
        int k = l + ((ki - 12) << 6);
        float x0 = h2s[k],        x1 = h2s[S2 + k],   x2 = h2s[2*S2 + k], x3 = h2s[3*S2 + k];
        float x4 = h2s[4*S2 + k], x5 = h2s[5*S2 + k], x6 = h2s[6*S2 + k], x7 = h2s[7*S2 + k];
        #pragma unroll
        for (int u = 0; u < 3; ++u){
          float w = wB[ki][u];
          acc[u][0] = fmaf(w, x0, acc[u][0]);
          acc[u][1] = fmaf(w, x1, acc[u][1]);
          acc[u][2] = fmaf(w, x2, acc[u][2]);
          acc[u][3] = fmaf(w, x3, acc[u][3]);
          acc[u][4] = fmaf(w, x4, acc[u][4]);
          acc[u][5] = fmaf(w, x5, acc[u][5]);
          acc[u][6] = fmaf(w, x6, acc[u][6]);
          acc[u][7] = fmaf(w, x7, acc[u][7]);
        }
      }
      #pragma unroll
      for (int i = 0; i < 12; ++i){
        int idx = tid + (i << 8);
        int k = idx >> 2, p = (idx & 3) << 1;
        xs[p*S2 + k]       = sa[i];
        xs[(p + 1)*S2 + k] = sb[i];
      }
      __syncthreads();
      #pragma unroll
      for (int ki = 0; ki < 12; ++ki){
        int k = l + (ki << 6);
        float x0 = xs[k],        x1 = xs[S2 + k],   x2 = xs[2*S2 + k], x3 = xs[3*S2 + k];
        float x4 = xs[4*S2 + k], x5 = xs[5*S2 + k], x6 = xs[6*S2 + k], x7 = xs[7*S2 + k];
        #pragma unroll
        for (int u = 0; u < 3; ++u){
          float w = wB[ki][u];
          acc[u][0] = fmaf(w, x0, acc[u][0]);
          acc[u][1] = fmaf(w, x1, acc[u][1]);
          acc[u][2] = fmaf(w, x2, acc[u][2]);
          acc[u][3] = fmaf(w, x3, acc[u][3]);
          acc[u][4] = fmaf(w, x4, acc[u][4]);
          acc[u][5] = fmaf(w, x5, acc[u][5]);
          acc[u][6] = fmaf(w, x6, acc[u][6]);
          acc[u][7] = fmaf(w, x7, acc[u][7]);
        }
      }
      #pragma unroll
      for (int u = 0; u < 3; ++u)
        #pragma unroll
        for (int j = 0; j < 8; ++j){
          float s = acc[u][j];
          s += __shfl_xor(s, 1);  s += __shfl_xor(s, 2);  s += __shfl_xor(s, 4);
          s += __shfl_xor(s, 8);  s += __shfl_xor(s, 16); s += __shfl_xor(s, 32);
          if (l == 0) zbuf[wv*24 + u*8 + j] = s;
        }
      __syncthreads();
      if (tid < 96)
        zbuf[tid] += b2r;
      __syncthreads();
      if (tid < 24){
        float zi = zbuf[tid], zf = zbuf[24 + tid], zg = zbuf[48 + tid], zo = zbuf[72 + tid];
        c2r = sigm(zf)*c2r + sigm(zi)*tanhf(zg);
        float hh = sigm(zo)*tanhf(c2r);
        cstore(&h2n[(wg*3 + (tid >> 3))*8 + (tid & 7)], hh);
      }
      ++bar; gbar(sy, bar, wg);
    }

    // ---- stage C' (NO barrier): stage h2s; wg<88 logits+argmax -> slot ----
    {
      float r0[8], r1[8], r2[8];
      #pragma unroll
      for (int q = 0; q < 4; ++q){
        cload64(h2n + (tid        )*8 + 2*q, r0[2*q], r0[2*q+1]);
        cload64(h2n + (tid + 256  )*8 + 2*q, r1[2*q], r1[2*q+1]);
        cload64(h2n + (tid + 512  )*8 + 2*q, r2[2*q], r2[2*q+1]);
      }
      #pragma unroll
      for (int p = 0; p < 8; ++p){
        h2s[p*S2 + tid]       = r0[p];
        h2s[p*S2 + tid + 256] = r1[p];
        h2s[p*S2 + tid + 512] = r2[p];
      }
      if (wg < 88){
        float acc[5][8];
        #pragma unroll
        for (int s = 0; s < 5; ++s)
          #pragma unroll
          for (int j = 0; j < 8; ++j)
            acc[s][j] = fmaf(wC[2][s], r2[j],
                        fmaf(wC[1][s], r1[j], wC[0][s]*r0[j]));
        #pragma unroll
        for (int s = 0; s < 5; ++s)
          #pragma unroll
          for (int j = 0; j < 8; ++j){
            float v = acc[s][j];
            v += __shfl_xor(v, 1);  v += __shfl_xor(v, 2);  v += __shfl_xor(v, 4);
            v += __shfl_xor(v, 8);  v += __shfl_xor(v, 16); v += __shfl_xor(v, 32);
            if (l == 0) red2[(s*8 + j)*4 + wv] = v;
          }
        __syncthreads();
        if (tid < 40){
          float sum = red2[tid*4] + red2[tid*4 + 1] + red2[tid*4 + 2] + red2[tid*4 + 3] + pbr;
          int s = tid >> 3, bb = tid & 7;
          out[bb*225280 + t*440 + wg*5 + s] = sum;
          zbuf[tid] = sum;
        }
        __syncthreads();
        int bs = 0;
        if (tid < 8){
          float best = zbuf[tid];
          #pragma unroll
          for (int s = 1; s < 5; ++s){
            float v = zbuf[s*8 + tid];
            if (v > best){ best = v; bs = s; }   // first max wins (jnp.argmax)
          }
        }
        if (wv == 0){
          unsigned lo = 0;
          #pragma unroll
          for (int b = 0; b < 8; ++b)
            lo |= (unsigned)(__shfl(bs, b) & 7) << (4*b);
          if (l == 0){
            unsigned long long pv =
                ((unsigned long long)(unsigned)(t + 1) << 32) | (unsigned long long)lo;
            cstoreu64(&sy[SLOTX + wg*16], pv);
          }
        }
      }
    }
  }
}

extern "C" void kernel_launch(void* const* d_in, const int* in_sizes, int n_in,
                              void* d_out, int out_size, void* d_ws, size_t ws_size,
                              hipStream_t stream)
{
  (void)in_sizes; (void)n_in; (void)out_size; (void)ws_size;
  const float* mel  = (const float*)d_in[0];
  const float* w1   = (const float*)d_in[1];
  const float* b1   = (const float*)d_in[2];
  const float* g1   = (const float*)d_in[3];
  const float* be1  = (const float*)d_in[4];
  const float* m1   = (const float*)d_in[5];
  const float* v1   = (const float*)d_in[6];
  const float* w2   = (const float*)d_in[7];
  const float* b2   = (const float*)d_in[8];
  const float* g2   = (const float*)d_in[9];
  const float* be2  = (const float*)d_in[10];
  const float* m2   = (const float*)d_in[11];
  const float* v2   = (const float*)d_in[12];
  const float* w3   = (const float*)d_in[13];
  const float* b3   = (const float*)d_in[14];
  const float* g3   = (const float*)d_in[15];
  const float* be3  = (const float*)d_in[16];
  const float* m3   = (const float*)d_in[17];
  const float* v3   = (const float*)d_in[18];
  const float* fcw  = (const float*)d_in[19];
  const float* fcb  = (const float*)d_in[20];
  const float* wih1 = (const float*)d_in[21];
  const float* whh1 = (const float*)d_in[22];
  const float* bih1 = (const float*)d_in[23];
  const float* bhh1 = (const float*)d_in[24];
  const float* wih2 = (const float*)d_in[25];
  const float* whh2 = (const float*)d_in[26];
  const float* bih2 = (const float*)d_in[27];
  const float* bhh2 = (const float*)d_in[28];
  const float* postw= (const float*)d_in[29];
  const float* postb= (const float*)d_in[30];
  const float* embw = (const float*)d_in[31];

  float* ws    = (float*)d_ws;
  float* c3p   = ws + WS_C3;
  float* c2ch  = ws + WS_C2CH;
  float* ac    = ws + WS_AC;
  float* A1    = ws + WS_A1;
  float* st    = ws + WS_ST;
  float* xbuf  = st;
  float* h2b   = st + 15104;
  unsigned* sy = (unsigned*)(st + 27392);
  float* outp  = (float*)d_out;

  // zero recurrent state + barrier slots/flags + 88 argmax slots
  // (27392 floats + 9616 u32 = 37008 floats)
  hipMemsetAsync(st, 0, 37008 * sizeof(float), stream);

  for (int c = 0; c < 4; ++c){
    int t0 = c * 128;
    conv2f_k<<<dim3(8*130), dim3(256), 0, stream>>>(
        mel, w1, b1, g1, be1, m1, v1, w2, b2, g2, be2, m2, v2, c2ch, t0);
    conv3_k<<<dim3(8*128), dim3(256), 0, stream>>>(
        c2ch, w3, b3, g3, be3, m3, v3, c3p, t0);
  }
  gemm_fc_k<<<dim3(32, 6), dim3(256), 0, stream>>>(c3p, fcw, fcb, ac);
  gemm_a1_k<<<dim3(32, 24), dim3(256), 0, stream>>>(ac, wih1, bih1, bhh1, A1);

  rec_k<<<dim3(256), dim3(256), 0, stream>>>(
      A1, whh1, wih1, wih2, whh2, bih2, bhh2, postw, postb, embw,
      xbuf, h2b, sy, outp);
}